// Round 1
// baseline (789.492 us; speedup 1.0000x reference)
//
#include <hip/hip_runtime.h>
#include <hip/hip_bf16.h>

// Problem constants
#define BB 16
#define TTOT 8192
#define MM 128
#define PP 128
#define NN 128
#define NCH 64      // chunks per batch
#define LCH 128     // chunk length (NCH*LCH == TTOT)

// ws layout (float offsets)
#define WS_LD_RE   0
#define WS_LD_IM   128
#define WS_LDL_RE  256
#define WS_LDL_IM  384
#define WS_BDT_RE  512                      // BdT[m][n], 16384
#define WS_BDT_IM  (512 + 16384)
#define WS_CT_RE   (512 + 32768)            // CT[n][p] = 2*C_re[p][n], 16384
#define WS_CT_IM   (512 + 32768 + 16384)    // CT[n][p] = 2*C_im[p][n]
#define WS_E_RE    (512 + 65536)            // E[b][c][n], 16*64*128
#define WS_E_IM    (WS_E_RE + 131072)
#define WS_CIN_RE  (WS_E_IM + 131072)
#define WS_CIN_IM  (WS_CIN_RE + 131072)

// K0: discretization in f64. grid 128 (n), block 128 (m / p)
__global__ void k0_setup(const float* __restrict__ lp, const float* __restrict__ bp,
                         const float* __restrict__ cp, const float* __restrict__ delta,
                         float* __restrict__ ws) {
    const int n = blockIdx.x;
    const int tid = threadIdx.x;
    const double d = (double)delta[0];
    const double lre = -exp((double)lp[n]);
    const double lim = (double)lp[128 + n];
    // Ld = exp(Lam*d)
    const double er = exp(lre * d);
    const double ldr = er * cos(lim * d);
    const double ldi = er * sin(lim * d);
    // Ld^L = exp(Lam*d*L)
    const double dl = d * (double)LCH;
    const double erl = exp(lre * dl);
    const double ldlr = erl * cos(lim * dl);
    const double ldli = erl * sin(lim * dl);
    // coef = (Ld - 1)/Lam
    const double nr = ldr - 1.0, ni = ldi;
    const double den = lre * lre + lim * lim;
    const double cr = (nr * lre + ni * lim) / den;
    const double ci = (ni * lre - nr * lim) / den;
    if (tid == 0) {
        ws[WS_LD_RE + n] = (float)ldr;   ws[WS_LD_IM + n] = (float)ldi;
        ws[WS_LDL_RE + n] = (float)ldlr; ws[WS_LDL_IM + n] = (float)ldli;
    }
    // BdT[m][n] = coef * Bc[n][m]
    const int m = tid;
    const double br = (double)bp[n * MM + m];
    const double bi = (double)bp[NN * MM + n * MM + m];
    ws[WS_BDT_RE + m * NN + n] = (float)(cr * br - ci * bi);
    ws[WS_BDT_IM + m * NN + n] = (float)(cr * bi + ci * br);
    // CT[n][p] = 2*C[p][n] (fold y = 2*Re(...))
    const int p = tid;
    ws[WS_CT_RE + n * PP + p] = 2.0f * cp[p * NN + n];
    ws[WS_CT_IM + n * PP + p] = 2.0f * cp[PP * NN + p * NN + n];
}

// K1: per-chunk zero-init local scan end-state E.
// 512 blocks x 256 threads; each half-block (2 waves) = one chunk, thread owns n.
__global__ __launch_bounds__(256) void k1_chunk_end(const float* __restrict__ u,
                                                    float* __restrict__ ws) {
    const int tid = threadIdx.x;
    const int half = tid >> 7;
    const int n = tid & 127;
    const int g = blockIdx.x * 2 + half;          // chunk id 0..1023
    const int b = g >> 6;
    const int c = g & 63;
    const int t0 = c * LCH;
    // wave-uniform u base -> scalar loads
    const int ub = __builtin_amdgcn_readfirstlane((b * TTOT + t0) * MM);
    const float* up = u + ub;
    const float ldr = ws[WS_LD_RE + n];
    const float ldi = ws[WS_LD_IM + n];
    float sr = 0.f, si = 0.f;
    for (int pass = 0; pass < 8; ++pass) {        // 16 t per pass
        float ar[16], ai[16];
#pragma unroll
        for (int i = 0; i < 16; ++i) { ar[i] = 0.f; ai[i] = 0.f; }
        const float* upp = up + pass * 16 * MM;
        for (int m4 = 0; m4 < 32; ++m4) {
            const int mb = m4 * 4;
            const float br0 = ws[WS_BDT_RE + (mb + 0) * NN + n];
            const float br1 = ws[WS_BDT_RE + (mb + 1) * NN + n];
            const float br2 = ws[WS_BDT_RE + (mb + 2) * NN + n];
            const float br3 = ws[WS_BDT_RE + (mb + 3) * NN + n];
            const float bi0 = ws[WS_BDT_IM + (mb + 0) * NN + n];
            const float bi1 = ws[WS_BDT_IM + (mb + 1) * NN + n];
            const float bi2 = ws[WS_BDT_IM + (mb + 2) * NN + n];
            const float bi3 = ws[WS_BDT_IM + (mb + 3) * NN + n];
#pragma unroll
            for (int tt = 0; tt < 16; ++tt) {
                const float4 uu = *(const float4*)(upp + tt * MM + mb);
                ar[tt] = fmaf(uu.x, br0, ar[tt]);
                ai[tt] = fmaf(uu.x, bi0, ai[tt]);
                ar[tt] = fmaf(uu.y, br1, ar[tt]);
                ai[tt] = fmaf(uu.y, bi1, ai[tt]);
                ar[tt] = fmaf(uu.z, br2, ar[tt]);
                ai[tt] = fmaf(uu.z, bi2, ai[tt]);
                ar[tt] = fmaf(uu.w, br3, ar[tt]);
                ai[tt] = fmaf(uu.w, bi3, ai[tt]);
            }
        }
#pragma unroll
        for (int tt = 0; tt < 16; ++tt) {
            const float nr = fmaf(ldr, sr, fmaf(-ldi, si, ar[tt]));
            const float ni = fmaf(ldr, si, fmaf(ldi, sr, ai[tt]));
            sr = nr; si = ni;
        }
    }
    ws[WS_E_RE + g * NN + n] = sr;
    ws[WS_E_IM + g * NN + n] = si;
}

// K2: chunk-level scan (exact: x_end[c] = Ld^L * x_end[c-1] + E[c]); writes carry_in.
__global__ void k2_carry(float* __restrict__ ws) {
    const int idx = blockIdx.x * 256 + threadIdx.x;   // 0..2047
    const int b = idx >> 7;
    const int n = idx & 127;
    const float lr = ws[WS_LDL_RE + n];
    const float li = ws[WS_LDL_IM + n];
    float cr = 0.f, ci = 0.f;
    for (int c = 0; c < NCH; ++c) {
        const int o = (b * NCH + c) * NN + n;
        ws[WS_CIN_RE + o] = cr;
        ws[WS_CIN_IM + o] = ci;
        const float er = ws[WS_E_RE + o];
        const float ei = ws[WS_E_IM + o];
        const float nr = fmaf(lr, cr, fmaf(-li, ci, er));
        const float ni = fmaf(lr, ci, fmaf(li, cr, ei));
        cr = nr; ci = ni;
    }
}

// K3: per chunk: recompute Bu -> LDS, scan with carry seed, output GEMM -> y.
// 1024 blocks x 256 threads (th = t-half, lid = n for gemm1/scan, p for gemm2).
__global__ __launch_bounds__(256) void k3_main(const float* __restrict__ u,
                                               float* __restrict__ ws,
                                               float* __restrict__ y) {
    __shared__ float2 xs[LCH * NN];                 // 128 KB: Bu then x, [t][n]
    const int tid = threadIdx.x;
    const int th = tid >> 7;
    const int lid = tid & 127;
    const int g = blockIdx.x;
    const int b = g >> 6;
    const int c = g & 63;
    const int t0 = c * LCH;
    const float* up = u + (size_t)(b * TTOT + t0) * MM;
    const float ldr = ws[WS_LD_RE + lid];
    const float ldi = ws[WS_LD_IM + lid];
    float sr = ws[WS_CIN_RE + g * NN + lid];
    float si = ws[WS_CIN_IM + g * NN + lid];
    for (int pass = 0; pass < 8; ++pass) {
        float ar[8], ai[8];
#pragma unroll
        for (int i = 0; i < 8; ++i) { ar[i] = 0.f; ai[i] = 0.f; }
        const int tp0 = pass * 16 + th * 8;
        const int uoff = __builtin_amdgcn_readfirstlane(tp0 * MM);
        const float* upp = up + uoff;
        for (int m4 = 0; m4 < 32; ++m4) {
            const int mb = m4 * 4;
            const float br0 = ws[WS_BDT_RE + (mb + 0) * NN + lid];
            const float br1 = ws[WS_BDT_RE + (mb + 1) * NN + lid];
            const float br2 = ws[WS_BDT_RE + (mb + 2) * NN + lid];
            const float br3 = ws[WS_BDT_RE + (mb + 3) * NN + lid];
            const float bi0 = ws[WS_BDT_IM + (mb + 0) * NN + lid];
            const float bi1 = ws[WS_BDT_IM + (mb + 1) * NN + lid];
            const float bi2 = ws[WS_BDT_IM + (mb + 2) * NN + lid];
            const float bi3 = ws[WS_BDT_IM + (mb + 3) * NN + lid];
#pragma unroll
            for (int tt = 0; tt < 8; ++tt) {
                const float4 uu = *(const float4*)(upp + tt * MM + mb);
                ar[tt] = fmaf(uu.x, br0, ar[tt]);
                ai[tt] = fmaf(uu.x, bi0, ai[tt]);
                ar[tt] = fmaf(uu.y, br1, ar[tt]);
                ai[tt] = fmaf(uu.y, bi1, ai[tt]);
                ar[tt] = fmaf(uu.z, br2, ar[tt]);
                ai[tt] = fmaf(uu.z, bi2, ai[tt]);
                ar[tt] = fmaf(uu.w, br3, ar[tt]);
                ai[tt] = fmaf(uu.w, bi3, ai[tt]);
            }
        }
#pragma unroll
        for (int tt = 0; tt < 8; ++tt) {
            xs[(tp0 + tt) * NN + lid] = make_float2(ar[tt], ai[tt]);
        }
        __syncthreads();
        if (th == 0) {   // serial scan over the 16 t of this pass, thread = n
#pragma unroll
            for (int tt = 0; tt < 16; ++tt) {
                const int t = pass * 16 + tt;
                const float2 bu = xs[t * NN + lid];
                const float nr = fmaf(ldr, sr, fmaf(-ldi, si, bu.x));
                const float ni = fmaf(ldr, si, fmaf(ldi, sr, bu.y));
                sr = nr; si = ni;
                xs[t * NN + lid] = make_float2(sr, si);
            }
        }
        __syncthreads();
    }
    // GEMM#2: y[t][p] = sum_n xr*CTr[n][p] - xi*CTi[n][p]   (factor 2 folded in CT)
    const int p = lid;
    for (int tile = 0; tile < 4; ++tile) {
        float acc[16];
#pragma unroll
        for (int i = 0; i < 16; ++i) acc[i] = 0.f;
        const int tb = th * 64 + tile * 16;
        const int tbu = __builtin_amdgcn_readfirstlane(tb);
        for (int j = 0; j < 64; ++j) {              // pairs of n
            const float cr0 = ws[WS_CT_RE + (2 * j) * PP + p];
            const float ci0 = ws[WS_CT_IM + (2 * j) * PP + p];
            const float cr1 = ws[WS_CT_RE + (2 * j + 1) * PP + p];
            const float ci1 = ws[WS_CT_IM + (2 * j + 1) * PP + p];
#pragma unroll
            for (int tt = 0; tt < 16; ++tt) {
                const float4 xv = *(const float4*)&xs[(tbu + tt) * NN + 2 * j];
                acc[tt] = fmaf(xv.x, cr0, acc[tt]);
                acc[tt] = fmaf(xv.y, -ci0, acc[tt]);
                acc[tt] = fmaf(xv.z, cr1, acc[tt]);
                acc[tt] = fmaf(xv.w, -ci1, acc[tt]);
            }
        }
#pragma unroll
        for (int tt = 0; tt < 16; ++tt) {
            y[(size_t)(b * TTOT + t0 + tb + tt) * PP + p] = acc[tt];
        }
    }
}

extern "C" void kernel_launch(void* const* d_in, const int* in_sizes, int n_in,
                              void* d_out, int out_size, void* d_ws, size_t ws_size,
                              hipStream_t stream) {
    const float* u     = (const float*)d_in[0];
    const float* lp    = (const float*)d_in[1];
    const float* bp    = (const float*)d_in[2];
    const float* cp    = (const float*)d_in[3];
    const float* delta = (const float*)d_in[4];
    float* y  = (float*)d_out;
    float* ws = (float*)d_ws;

    k0_setup<<<128, 128, 0, stream>>>(lp, bp, cp, delta, ws);
    k1_chunk_end<<<512, 256, 0, stream>>>(u, ws);
    k2_carry<<<8, 256, 0, stream>>>(ws);
    k3_main<<<1024, 256, 0, stream>>>(u, ws, y);
}

// Round 2
// 98.828 us; speedup vs baseline: 7.9885x; 7.9885x over previous
//
#include <hip/hip_runtime.h>
#include <hip/hip_bf16.h>

// Problem constants: B=16, T=8192, M=P=128, N2=128. Chunks: 64 per batch, L=128.
#define LCH 128
#define NCH 64
#define NCHUNKS 1024   // 16*64

typedef __attribute__((ext_vector_type(8))) short short8v;
typedef __attribute__((ext_vector_type(4))) short short4v;
typedef __attribute__((ext_vector_type(4))) float f32x4;

// ws layout (float offsets for f32 region)
#define WS_LDINV_RE 0                       // [128 r][128 n]  Ld^{-(r+1)}
#define WS_LDINV_IM 16384
#define WS_LDP_RE   32768                   // [128 r][128 n]  Ld^{r+1}
#define WS_LDP_IM   49152
#define WS_E_RE     65536                   // [1024 g][128 n]
#define WS_E_IM     (65536 + 131072)
#define WS_CIN_RE   (65536 + 262144)
#define WS_CIN_IM   (65536 + 393216)
#define WS_F32_END  (65536 + 524288)        // 589824 floats
#define WS_WPACK_BYTE  (589824 * 4)         // 32768 bf16 (64 KB): [ntile16][ks4][lane64][j8]
#define WS_CCPACK_BYTE (589824 * 4 + 65536) // 32768 bf16: [ptile8][ks8][lane64][j8]

__device__ inline unsigned short f2bf(float f) {
    union { float f; unsigned u; } v; v.f = f;
    unsigned r = v.u + 0x7FFF + ((v.u >> 16) & 1);   // RNE
    return (unsigned short)(r >> 16);
}

// ---------------- k0a: power tables (f64 exact) ----------------
__global__ void k0_pows(const float* __restrict__ lp, const float* __restrict__ delta,
                        float* __restrict__ ws) {
    const int r = blockIdx.x;          // 0..127
    const int tid = threadIdx.x;       // 0..255
    const int n = tid & 127;
    const double d = (double)delta[0];
    const double lre = -exp((double)lp[n]);
    const double lim = (double)lp[128 + n];
    const double kk = (double)(r + 1) * d;
    if (tid < 128) {                   // Ldinv[r][n] = Ld^{-(r+1)} = exp(-Lam*kk)
        const double mag = exp(-lre * kk);
        ws[WS_LDINV_RE + r * 128 + n] = (float)(mag * cos(lim * kk));
        ws[WS_LDINV_IM + r * 128 + n] = (float)(-mag * sin(lim * kk));
    } else {                           // Ldp[r][n] = Ld^{r+1} = exp(Lam*kk)
        const double mag = exp(lre * kk);
        ws[WS_LDP_RE + r * 128 + n] = (float)(mag * cos(lim * kk));
        ws[WS_LDP_IM + r * 128 + n] = (float)(mag * sin(lim * kk));
    }
}

// ---------------- k0b: pack W = Bd^T as B-fragments ----------------
// W[m, n'] : n'<128 -> Re(Bd[n'][m]), else Im(Bd[n'-128][m]).
// frag layout: value at (ntile, ks, lane, j) = W[ks*32+(lane>>4)*8+j, ntile*16+(lane&15)]
__global__ void k0_wpack(const float* __restrict__ lp, const float* __restrict__ bp,
                         const float* __restrict__ delta, unsigned short* __restrict__ wpack) {
    const int gid = blockIdx.x * 512 + threadIdx.x;    // 0..32767
    const int j = gid & 7;
    const int lane = (gid >> 3) & 63;
    const int ks = (gid >> 9) & 3;
    const int ntile = gid >> 11;
    const int np = ntile * 16 + (lane & 15);
    const int m = ks * 32 + ((lane >> 4) & 3) * 8 + j;
    const int n = np & 127;
    const double d = (double)delta[0];
    const double lre = -exp((double)lp[n]);
    const double lim = (double)lp[128 + n];
    const double er = exp(lre * d);
    const double ldr = er * cos(lim * d), ldi = er * sin(lim * d);
    const double nr = ldr - 1.0, ni = ldi;
    const double den = lre * lre + lim * lim;
    const double cr = (nr * lre + ni * lim) / den;
    const double ci = (ni * lre - nr * lim) / den;
    const double br = (double)bp[n * 128 + m];
    const double bi = (double)bp[16384 + n * 128 + m];
    const double v = (np < 128) ? (cr * br - ci * bi) : (cr * bi + ci * br);
    wpack[gid] = f2bf((float)v);
}

// ---------------- k0c: pack CC (K=256, re/im interleaved along k) ----------------
// CC[k=2n+0, p] = 2*C_re[p][n] ; CC[k=2n+1, p] = -2*C_im[p][n]
__global__ void k0_cpack(const float* __restrict__ cp, unsigned short* __restrict__ ccpack) {
    const int gid = blockIdx.x * 512 + threadIdx.x;    // 0..32767
    const int j = gid & 7;
    const int lane = (gid >> 3) & 63;
    const int ks = (gid >> 9) & 7;
    const int ptile = gid >> 12;
    const int p = ptile * 16 + (lane & 15);
    const int k = ks * 32 + ((lane >> 4) & 3) * 8 + j;
    const int n = k >> 1;
    const float v = ((k & 1) == 0) ? 2.0f * cp[p * 128 + n] : -2.0f * cp[16384 + p * 128 + n];
    ccpack[gid] = f2bf(v);
}

// ---------------- shared device helpers ----------------
// stage u chunk (128t x 128m f32) -> LDS bf16 [t][m], swizzle byte ^= (t&7)<<4
__device__ inline void stage_u(const float* __restrict__ uchunk, unsigned short* lds_u) {
    const float4* uf = (const float4*)uchunk;
    const int tid = threadIdx.x;
#pragma unroll
    for (int it = 0; it < 8; ++it) {
        const int f4 = it * 512 + tid;
        const float4 v = uf[f4];
        const int e = f4 * 4;
        const int t = e >> 7;
        const int m = e & 127;
        const int byte = (t * 256 + m * 2) ^ ((t & 7) << 4);
        short4v wv;
        wv[0] = (short)f2bf(v.x); wv[1] = (short)f2bf(v.y);
        wv[2] = (short)f2bf(v.z); wv[3] = (short)f2bf(v.w);
        *(short4v*)((char*)lds_u + byte) = wv;
    }
}

// GEMM1: Bu[t, n'] for wave w: cols n' in [16w,16w+16) (re, frag 0) and [128+16w, ...) (im, frag 1)
__device__ inline void gemm1(const unsigned short* lds_u, const unsigned short* wpack,
                             int w, int lane, f32x4 acc[8][2]) {
    const short8v* wp = (const short8v*)wpack;
    const int tl = lane & 15;
    const int gq = (lane >> 4) & 3;
#pragma unroll
    for (int ks = 0; ks < 4; ++ks) {
        const short8v b0 = wp[(w * 4 + ks) * 64 + lane];
        const short8v b1 = wp[((8 + w) * 4 + ks) * 64 + lane];
#pragma unroll
        for (int tt = 0; tt < 8; ++tt) {
            const int t = tt * 16 + tl;
            const int byte = (t * 256 + (ks * 32 + gq * 8) * 2) ^ ((t & 7) << 4);
            const short8v a = *(const short8v*)((const char*)lds_u + byte);
            acc[tt][0] = __builtin_amdgcn_mfma_f32_16x16x32_bf16(a, b0, acc[tt][0], 0, 0, 0);
            acc[tt][1] = __builtin_amdgcn_mfma_f32_16x16x32_bf16(a, b1, acc[tt][1], 0, 0, 0);
        }
    }
}

// ---------------- k1: chunk end-states E (zero-init) ----------------
__global__ __launch_bounds__(512) void k1_end(const float* __restrict__ u,
                                              float* __restrict__ ws,
                                              const unsigned short* __restrict__ wpack) {
    __shared__ unsigned short lds_u[16384];
    const int tid = threadIdx.x;
    const int lane = tid & 63;
    const int w = tid >> 6;
    const int g = blockIdx.x;
    const int b = g >> 6;
    const int c = g & 63;
    stage_u(u + (size_t)(b * 8192 + c * 128) * 128, lds_u);
    __syncthreads();
    f32x4 acc[8][2];
#pragma unroll
    for (int i = 0; i < 8; ++i) { acc[i][0] = (f32x4)0.f; acc[i][1] = (f32x4)0.f; }
    gemm1(lds_u, wpack, w, lane, acc);
    // E[n] = Ld^128 * sum_r Ldinv[r] (.) Bu[r,n]
    const int tl = lane & 15;
    const int gq = (lane >> 4) & 3;
    const int n = w * 16 + tl;
    float er = 0.f, ei = 0.f;
#pragma unroll
    for (int tt = 0; tt < 8; ++tt) {
#pragma unroll
        for (int reg = 0; reg < 4; ++reg) {
            const int r = tt * 16 + gq * 4 + reg;
            const float lir = ws[WS_LDINV_RE + r * 128 + n];
            const float lii = ws[WS_LDINV_IM + r * 128 + n];
            const float br = acc[tt][0][reg], bi = acc[tt][1][reg];
            er += lir * br - lii * bi;
            ei += lir * bi + lii * br;
        }
    }
    er += __shfl_xor(er, 16); ei += __shfl_xor(ei, 16);
    er += __shfl_xor(er, 32); ei += __shfl_xor(ei, 32);
    const float ldr = ws[WS_LDP_RE + 127 * 128 + n];
    const float ldi = ws[WS_LDP_IM + 127 * 128 + n];
    if (gq == 0 && (lane >> 4) == 0) {
        ws[WS_E_RE + g * 128 + n] = ldr * er - ldi * ei;
        ws[WS_E_IM + g * 128 + n] = ldr * ei + ldi * er;
    }
}

// ---------------- k2: chunk-level scan -> carry-in ----------------
__global__ void k2_carry(float* __restrict__ ws) {
    const int idx = blockIdx.x * 256 + threadIdx.x;   // 0..2047
    const int b = idx >> 7;
    const int n = idx & 127;
    const float lr = ws[WS_LDP_RE + 127 * 128 + n];
    const float li = ws[WS_LDP_IM + 127 * 128 + n];
    float cr = 0.f, ci = 0.f;
    for (int c = 0; c < NCH; ++c) {
        const int o = (b * NCH + c) * 128 + n;
        ws[WS_CIN_RE + o] = cr;
        ws[WS_CIN_IM + o] = ci;
        const float er = ws[WS_E_RE + o];
        const float ei = ws[WS_E_IM + o];
        const float nr = fmaf(lr, cr, fmaf(-li, ci, er));
        const float ni = fmaf(lr, ci, fmaf(li, cr, ei));
        cr = nr; ci = ni;
    }
}

// ---------------- k3: GEMM1 -> scale -> tri-cumsum MFMA -> scale+carry -> GEMM3 ----------------
__global__ __launch_bounds__(512) void k3_main(const float* __restrict__ u,
                                               float* __restrict__ ws,
                                               const unsigned short* __restrict__ wpack,
                                               const unsigned short* __restrict__ ccpack,
                                               float* __restrict__ y) {
    __shared__ unsigned short lds[49152];     // 96 KB: [0,16384)=u ; [16384,49152)=bus ; x aliases [0,32768)
    unsigned short* lds_u = lds;
    unsigned short* lds_bus = lds + 16384;
    const int tid = threadIdx.x;
    const int lane = tid & 63;
    const int w = tid >> 6;
    const int tl = lane & 15;
    const int gq = (lane >> 4) & 3;
    const int g = blockIdx.x;
    const int b = g >> 6;
    const int c = g & 63;
    const int n = w * 16 + tl;

    stage_u(u + (size_t)(b * 8192 + c * 128) * 128, lds_u);
    __syncthreads();

    // GEMM1
    f32x4 acc[8][2];
#pragma unroll
    for (int i = 0; i < 8; ++i) { acc[i][0] = (f32x4)0.f; acc[i][1] = (f32x4)0.f; }
    gemm1(lds_u, wpack, w, lane, acc);

    // scale by Ldinv, write Bus_T [n'][s] bf16 (re rows 0..127, im rows 128..255)
#pragma unroll
    for (int tt = 0; tt < 8; ++tt) {
        short4v pr, pi;
#pragma unroll
        for (int reg = 0; reg < 4; ++reg) {
            const int r = tt * 16 + gq * 4 + reg;
            const float lir = ws[WS_LDINV_RE + r * 128 + n];
            const float lii = ws[WS_LDINV_IM + r * 128 + n];
            const float br = acc[tt][0][reg], bi = acc[tt][1][reg];
            pr[reg] = (short)f2bf(lir * br - lii * bi);
            pi[reg] = (short)f2bf(lir * bi + lii * br);
        }
        const int s0 = tt * 16 + gq * 4;
        const int rowr = w * 16 + tl;
        *(short4v*)((char*)lds_bus + ((rowr * 256 + s0 * 2) ^ ((rowr & 7) << 4))) = pr;
        const int rowi = 128 + w * 16 + tl;
        *(short4v*)((char*)lds_bus + ((rowi * 256 + s0 * 2) ^ ((rowi & 7) << 4))) = pi;
    }

    // GEMM2: z = T_lower_ones x Bus  (same-wave LDS data; no barrier needed)
    short8v ONES, D0, D1;
#pragma unroll
    for (int j = 0; j < 8; ++j) {
        const int sl = gq * 8 + j;
        ONES[j] = (short)0x3F80;
        D0[j] = (sl <= tl) ? (short)0x3F80 : (short)0;
        D1[j] = (sl <= tl + 16) ? (short)0x3F80 : (short)0;
    }
    f32x4 z[8][2];
#pragma unroll
    for (int i = 0; i < 8; ++i) { z[i][0] = (f32x4)0.f; z[i][1] = (f32x4)0.f; }
#pragma unroll
    for (int ks = 0; ks < 4; ++ks) {
        const int rr = w * 16 + tl;
        const short8v b0 = *(const short8v*)((const char*)lds_bus +
                           ((rr * 256 + (ks * 32 + gq * 8) * 2) ^ ((rr & 7) << 4)));
        const int ri = 128 + w * 16 + tl;
        const short8v b1 = *(const short8v*)((const char*)lds_bus +
                           ((ri * 256 + (ks * 32 + gq * 8) * 2) ^ ((ri & 7) << 4)));
#pragma unroll
        for (int tt = 0; tt < 8; ++tt) {
            if (tt < 2 * ks) continue;                  // zero block
            const short8v a = (tt == 2 * ks) ? D0 : ((tt == 2 * ks + 1) ? D1 : ONES);
            z[tt][0] = __builtin_amdgcn_mfma_f32_16x16x32_bf16(a, b0, z[tt][0], 0, 0, 0);
            z[tt][1] = __builtin_amdgcn_mfma_f32_16x16x32_bf16(a, b1, z[tt][1], 0, 0, 0);
        }
    }
    __syncthreads();   // all waves finished reading bus (x overwrites below)

    // x[t][k''] = Ldp[t] (.) (z + carry), interleaved re/im along k''=2n+parity
    const float cr = ws[WS_CIN_RE + g * 128 + n];
    const float ci = ws[WS_CIN_IM + g * 128 + n];
#pragma unroll
    for (int tt = 0; tt < 8; ++tt) {
#pragma unroll
        for (int reg = 0; reg < 4; ++reg) {
            const int r = tt * 16 + gq * 4 + reg;
            const float ldr = ws[WS_LDP_RE + r * 128 + n];
            const float ldi = ws[WS_LDP_IM + r * 128 + n];
            const float zr = z[tt][0][reg] + cr;
            const float zi = z[tt][1][reg] + ci;
            const float xr = ldr * zr - ldi * zi;
            const float xi = ldr * zi + ldi * zr;
            const unsigned pack = (unsigned)f2bf(xr) | ((unsigned)f2bf(xi) << 16);
            const int byte = (r * 512 + n * 4) ^ ((r & 7) << 4);
            *(unsigned*)((char*)lds + byte) = pack;
        }
    }
    __syncthreads();

    // GEMM3: y[t][p] ; wave w owns p-tile w, all t
    const short8v* cc = (const short8v*)ccpack;
    f32x4 yac[8];
#pragma unroll
    for (int i = 0; i < 8; ++i) yac[i] = (f32x4)0.f;
#pragma unroll
    for (int ks = 0; ks < 8; ++ks) {
        const short8v bfrg = cc[(w * 8 + ks) * 64 + lane];
#pragma unroll
        for (int tt = 0; tt < 8; ++tt) {
            const int t = tt * 16 + tl;
            const int byte = (t * 512 + (ks * 32 + gq * 8) * 2) ^ ((t & 7) << 4);
            const short8v a = *(const short8v*)((const char*)lds + byte);
            yac[tt] = __builtin_amdgcn_mfma_f32_16x16x32_bf16(a, bfrg, yac[tt], 0, 0, 0);
        }
    }
    // store y (f32)
    const int p = w * 16 + tl;
    float* yrow = y + (size_t)(b * 8192 + c * 128) * 128;
#pragma unroll
    for (int tt = 0; tt < 8; ++tt) {
#pragma unroll
        for (int reg = 0; reg < 4; ++reg) {
            const int t = tt * 16 + gq * 4 + reg;
            yrow[t * 128 + p] = yac[tt][reg];
        }
    }
}

extern "C" void kernel_launch(void* const* d_in, const int* in_sizes, int n_in,
                              void* d_out, int out_size, void* d_ws, size_t ws_size,
                              hipStream_t stream) {
    const float* u     = (const float*)d_in[0];
    const float* lp    = (const float*)d_in[1];
    const float* bp    = (const float*)d_in[2];
    const float* cp    = (const float*)d_in[3];
    const float* delta = (const float*)d_in[4];
    float* y  = (float*)d_out;
    float* ws = (float*)d_ws;
    unsigned short* wpack  = (unsigned short*)((char*)d_ws + WS_WPACK_BYTE);
    unsigned short* ccpack = (unsigned short*)((char*)d_ws + WS_CCPACK_BYTE);

    k0_pows <<<128, 256, 0, stream>>>(lp, delta, ws);
    k0_wpack<<<64, 512, 0, stream>>>(lp, bp, delta, wpack);
    k0_cpack<<<64, 512, 0, stream>>>(cp, ccpack);
    k1_end  <<<NCHUNKS, 512, 0, stream>>>(u, ws, wpack);
    k2_carry<<<8, 256, 0, stream>>>(ws);
    k3_main <<<NCHUNKS, 512, 0, stream>>>(u, ws, wpack, ccpack, y);
}